// Round 6
// baseline (77.521 us; speedup 1.0000x reference)
//
#include <hip/hip_runtime.h>
#include <math.h>

// ---------- types ----------
typedef __bf16 bf16x8 __attribute__((ext_vector_type(8)));
typedef float f32x4 __attribute__((ext_vector_type(4)));
typedef float f32x16 __attribute__((ext_vector_type(16)));
typedef unsigned int u32x4 __attribute__((ext_vector_type(4)));
typedef unsigned short u16x8 __attribute__((ext_vector_type(8)));

#define B_ 4
#define T_ 4096
#define C_ 1024
#define H_ 128

static __device__ __forceinline__ unsigned short f32_to_bf16(float f) {
  unsigned int u = __builtin_bit_cast(unsigned int, f);
  u += 0x7FFFu + ((u >> 16) & 1u);   // RNE
  return (unsigned short)(u >> 16);
}
static __device__ __forceinline__ float bf16_to_f32(unsigned short u) {
  unsigned int x = ((unsigned int)u) << 16;
  return __builtin_bit_cast(float, x);
}

static __device__ __forceinline__ bf16x8 ld16g(const unsigned short* p) {
  return __builtin_bit_cast(bf16x8, *(const u32x4*)p);
}

static __device__ __forceinline__ f32x4 mfma16(bf16x8 a, bf16x8 b, f32x4 c) {
  return __builtin_amdgcn_mfma_f32_16x16x32_bf16(a, b, c, 0, 0, 0);
}
static __device__ __forceinline__ f32x16 mfma32(bf16x8 a, bf16x8 b, f32x16 c) {
  return __builtin_amdgcn_mfma_f32_32x32x16_bf16(a, b, c, 0, 0, 0);
}

// v_permlane32_swap_b32: ONLY safe when a and b hold DIFFERENT values
// (R4 bug: identical SSA values coalesce onto one VGPR and the swap no-ops).
static __device__ __forceinline__ void swapu(unsigned int& a, unsigned int& b) {
  asm volatile("v_permlane32_swap_b32 %0, %1" : "+v"(a), "+v"(b));
}
static __device__ __forceinline__ unsigned int cvtpk(float lo, float hi) {
  unsigned int r;
  asm("v_cvt_pk_bf16_f32 %0, %1, %2" : "=v"(r) : "v"(lo), "v"(hi));
  return r;
}
// single f32 -> bf16 via v_cvt_pk (RNE, 1 VALU op vs ~4 for the bit-twiddle)
static __device__ __forceinline__ unsigned short cvt1(float v) {
  return (unsigned short)cvtpk(v, v);
}
static __device__ __forceinline__ float bpermf(int addr, float v) {
  return __builtin_bit_cast(float, __builtin_amdgcn_ds_bpermute(addr, __builtin_bit_cast(int, v)));
}
static __device__ __forceinline__ float half_merge_max(float x) {
  return fmaxf(x, __shfl_xor(x, 32));
}
static __device__ __forceinline__ float half_merge_sum(float x) {
  return x + __shfl_xor(x, 32);
}
static __device__ __forceinline__ float vmax16(f32x16 v) {
  float a0 = fmaxf(v[0], v[1]),  a1 = fmaxf(v[2], v[3]);
  float a2 = fmaxf(v[4], v[5]),  a3 = fmaxf(v[6], v[7]);
  float a4 = fmaxf(v[8], v[9]),  a5 = fmaxf(v[10], v[11]);
  float a6 = fmaxf(v[12], v[13]), a7 = fmaxf(v[14], v[15]);
  float b0 = fmaxf(a0, a1), b1 = fmaxf(a2, a3), b2 = fmaxf(a4, a5), b3 = fmaxf(a6, a7);
  return fmaxf(fmaxf(b0, b1), fmaxf(b2, b3));
}
static __device__ __forceinline__ float vsum16(f32x16 v) {
  float a0 = v[0] + v[1],  a1 = v[2] + v[3],  a2 = v[4] + v[5],  a3 = v[6] + v[7];
  float a4 = v[8] + v[9],  a5 = v[10] + v[11], a6 = v[12] + v[13], a7 = v[14] + v[15];
  float b0 = a0 + a1, b1 = a2 + a3, b2 = a4 + a5, b3 = a6 + a7;
  return (b0 + b1) + (b2 + b3);
}

typedef __attribute__((address_space(1))) const unsigned char as1_u8;
typedef __attribute__((address_space(3))) unsigned char as3_u8;
static __device__ __forceinline__ void async16(const void* g, void* l) {
  __builtin_amdgcn_global_load_lds((as1_u8*)g, (as3_u8*)l, 16, 0, 0);
}

// 8 f32 -> 8 bf16 via 4x v_cvt_pk_bf16_f32 (RNE, element order preserved).
static __device__ __forceinline__ u16x8 pack8cvt(float4 a, float4 b) {
  u32x4 u;
  u[0] = cvtpk(a.x, a.y); u[1] = cvtpk(a.z, a.w);
  u[2] = cvtpk(b.x, b.y); u[3] = cvtpk(b.z, b.w);
  return __builtin_bit_cast(u16x8, u);
}

#define PART_BYTES 33792   // bf16 O[128][128] (32768) + f32 m[128] (512) + f32 l[128] (512)

// ---------- kernel 1: W -> WT bf16 transposed; Wq scaled by log2e/sqrt(H) ----------
__global__ __launch_bounds__(256) void conv_w_kernel(const float* __restrict__ W0,
                                                     const float* __restrict__ W1,
                                                     const float* __restrict__ W2,
                                                     unsigned short* __restrict__ WT,
                                                     float qscale) {
  int tid = blockIdx.x * 256 + threadIdx.x;
  int o = tid >> 17;
  int r = tid & 131071;
  int n = r & 127;
  int k = r >> 7;
  const float* W = (o == 0) ? W0 : ((o == 1) ? W1 : W2);
  float v = W[r];
  if (o == 0) v *= qscale;
  WT[(size_t)o * 131072 + (size_t)n * 1024 + k] = f32_to_bf16(v);
}

// ---------- kernel 2: fused X-convert + QKV projection (128x128 tile, BK=128) ----------
// R6: BK 64 -> 128 — the ONE axis untouched in R0-R5. Six-experiment ledger
// says qkv is latency-EVENT-bound (per-k-step stage->wait->MFMA chain costs
// ~const regardless of pipelining/occupancy/geometry). Halving the step count
// (16->8) halves chain traversals; MFMA per chain doubles (64/wave/step).
// LDS 64KB (At+Bt 32KB each) — grid 384 runs ~1.5 blocks/CU (grid-limited),
// so the m132 occupancy-cliff objection to BK=128 doesn't apply here.
// Swizzle keys widen 3->4 bits (row&15): A write XOR + read XOR, B source
// pre-swizzle + read XOR use the same involution (stored slot t = global slot
// t^key; all read rows have row&15 == l15). k-chunk accumulation order
// unchanged (ks*4+kk sequence == old ks*2+kk) -> bit-identical numerics.
__global__ __launch_bounds__(256) void qkv_fused_kernel(const float* __restrict__ X,
                                                        const unsigned short* __restrict__ WT,
                                                        unsigned short* __restrict__ Qb,
                                                        unsigned short* __restrict__ K3,
                                                        unsigned short* __restrict__ V3) {
  __shared__ __align__(16) unsigned short At[128 * 128];   // 32KB
  __shared__ __align__(16) unsigned short Bt[128 * 128];   // 32KB
  const int bid = blockIdx.x;
  const int xcd = bid & 7, ii = bid >> 3;   // ii 0..47
  const int o = ii % 3;
  const int tile = (ii / 3) * 8 + xcd;      // 0..127

  const float* Ax = X + (size_t)tile * 128 * 1024;
  const unsigned short* Bsrc = WT + (size_t)o * 131072;

  const int tid = threadIdx.x;
  const int lane = tid & 63, wid = tid >> 6;
  const int l15 = lane & 15, lg = lane >> 4;
  const int wm = wid >> 1, wn = wid & 1;

  // ---- A staging geometry: row = i4*32 + srow, lane covers 16 f32 ----
  const int srow = wid * 8 + (lane >> 3);       // row within 32-row chunk
  const int sacol = (lane & 7) * 16;            // f32 col base (16 consecutive)
  const int akey = srow & 15;                   // swizzle key (i4*32 preserves &15)
  const int as0 = (lane & 7) * 2;               // first 8-elem slot
  const int aw0 = ((as0 ^ akey) << 3);          // swizzled elem offsets
  const int aw1 = (((as0 + 1) ^ akey) << 3);

  // ---- B staging geometry: 8 async16/wave, j-th covers rows wid*32+j*4+(lane>>4) ----
  const int brow_in = lane >> 4;                // 0..3 within async16
  const int bslot = lane & 15;                  // dest slot (linear)

  // ---- read-side ----
  const int rkey8 = l15 << 3;                   // (row&15)*8 elem XOR (row&15==l15)

  const f32x4 fzero = {0.f, 0.f, 0.f, 0.f};
  f32x4 acc[4][4];
#pragma unroll
  for (int i = 0; i < 4; i++)
#pragma unroll
    for (int j = 0; j < 4; j++) acc[i][j] = fzero;

  // A reg-prefetch for k-step 0 (16 f32 per lane per i4-chunk)
  float4 fA[4][4];
#pragma unroll
  for (int i4 = 0; i4 < 4; i4++) {
    const float* xs = Ax + (size_t)(i4 * 32 + srow) * 1024 + sacol;
    fA[i4][0] = *(const float4*)xs;
    fA[i4][1] = *(const float4*)(xs + 4);
    fA[i4][2] = *(const float4*)(xs + 8);
    fA[i4][3] = *(const float4*)(xs + 12);
  }

  for (int ks = 0; ks < 8; ks++) {
    const int k0 = ks * 128;
    __syncthreads();   // previous MFMA LDS reads complete
    // stage B: 8 async16 (pre-swizzled global src -> linear LDS dest)
#pragma unroll
    for (int j = 0; j < 8; j++) {
      const int row = wid * 32 + j * 4 + brow_in;
      const int key = (j * 4 + brow_in) & 15;   // row&15 (wid*32 preserves &15)
      async16(Bsrc + (size_t)row * 1024 + k0 + ((bslot ^ key) << 3),
              &Bt[(wid * 32 + j * 4) * 128]);
    }
    // stage A (convert + swizzled ds_write, 2 writes per lane per i4)
#pragma unroll
    for (int i4 = 0; i4 < 4; i4++) {
      unsigned short* dst = &At[(i4 * 32 + srow) * 128];
      *(u16x8*)(dst + aw0) = pack8cvt(fA[i4][0], fA[i4][1]);
      *(u16x8*)(dst + aw1) = pack8cvt(fA[i4][2], fA[i4][3]);
    }
    __syncthreads();   // drains vmcnt (B) + lgkmcnt (A writes)
    // prefetch next k-step's A f32 (latency hidden under 64 MFMA)
    if (ks + 1 < 8) {
#pragma unroll
      for (int i4 = 0; i4 < 4; i4++) {
        const float* xs = Ax + (size_t)(i4 * 32 + srow) * 1024 + (ks + 1) * 128 + sacol;
        fA[i4][0] = *(const float4*)xs;
        fA[i4][1] = *(const float4*)(xs + 4);
        fA[i4][2] = *(const float4*)(xs + 8);
        fA[i4][3] = *(const float4*)(xs + 12);
      }
    }
#pragma unroll
    for (int kk = 0; kk < 4; kk++) {
      bf16x8 af[4], bfr[4];
#pragma unroll
      for (int i = 0; i < 4; i++)
        af[i] = ld16g(&At[(wm * 64 + i * 16 + l15) * 128 + ((kk * 32 + lg * 8) ^ rkey8)]);
#pragma unroll
      for (int j = 0; j < 4; j++)
        bfr[j] = ld16g(&Bt[(wn * 64 + j * 16 + l15) * 128 + ((kk * 32 + lg * 8) ^ rkey8)]);
      __builtin_amdgcn_s_setprio(1);
#pragma unroll
      for (int i = 0; i < 4; i++)
#pragma unroll
        for (int j = 0; j < 4; j++) acc[i][j] = mfma16(af[i], bfr[j], acc[i][j]);
      __builtin_amdgcn_s_setprio(0);
    }
  }

  if (o == 0) {
#pragma unroll
    for (int i = 0; i < 4; i++)
#pragma unroll
      for (int j = 0; j < 4; j++)
#pragma unroll
        for (int r = 0; r < 4; r++) {
          int row = tile * 128 + wm * 64 + i * 16 + lg * 4 + r;
          int col = wn * 64 + j * 16 + l15;
          Qb[(size_t)row * 128 + col] = cvt1(acc[i][j][r]);
        }
  } else if (o == 1) {
#pragma unroll
    for (int i = 0; i < 4; i++)
#pragma unroll
      for (int j = 0; j < 4; j++)
#pragma unroll
        for (int r = 0; r < 4; r++) {
          int token = tile * 128 + wm * 64 + i * 16 + lg * 4 + r;
          int d = wn * 64 + j * 16 + l15;
          int bb = token >> 12, t = token & 4095;
          int t32 = t >> 5;
          int lane2 = (t & 31) | (((d >> 3) & 1) << 5);
          int c = d >> 4;
          int j2 = d & 7;
          K3[(size_t)(((bb * 128 + t32) * 8 + c) * 64 + lane2) * 8 + j2] = cvt1(acc[i][j][r]);
        }
  } else {
    // V: acc row = token, col = d
#pragma unroll
    for (int i = 0; i < 4; i++)
#pragma unroll
      for (int j = 0; j < 4; j++)
#pragma unroll
        for (int r = 0; r < 4; r++) {
          int token = tile * 128 + wm * 64 + i * 16 + lg * 4 + r;
          int d = wn * 64 + j * 16 + l15;
          int bb = token >> 12, tt = token & 4095;
          int t32 = tt >> 5;
          int kss = (tt >> 4) & 1;
          int hi2 = (tt >> 3) & 1;
          int j2 = tt & 7;
          int dt = d >> 5;
          int lane2 = (d & 31) | (hi2 << 5);
          V3[(size_t)(((bb * 128 + t32) * 8 + dt * 2 + kss) * 64 + lane2) * 8 + j2] = cvt1(acc[i][j][r]);
        }
  }
}

// ---------- kernel 3: causal flash attention, 128-row blocks, shared KV tile ----------
// Grid 768 = 4b x 32 q-tiles(128 rows) x 6 kv-slots; 4 warps = 4 qg share one
// 32-token KV tile per round (16KB staging, 32KB dbuf). Counted vmcnt(4) + raw
// barriers (T3/T4); in-reg swapped-QK softmax + T12 P-pack + T13 defer-max.
// Partial: bf16 O + f32 m/l -> Pw; separate merge kernel combines (the fused
// last-block merge regressed 2.6x — __threadfence() = per-block L2 flush on
// non-coherent XCDs, R20 post-mortem).
__global__ __launch_bounds__(256, 2) void attn_kernel(const unsigned short* __restrict__ Qb,
                                                      const unsigned short* __restrict__ K3,
                                                      const unsigned short* __restrict__ V3,
                                                      unsigned char* __restrict__ Pw8) {
  const int bid = blockIdx.x;
  const int xcd = bid & 7;
  const int b = xcd >> 1;
  const int rest = bid >> 3;                  // 0..95
  const int h = rest % 6;                     // kv slot
  const int jj = rest / 6;                    // 0..15
  const int g = (xcd & 1) + 2 * (15 - jj);    // q-tile 0..31, heavy-first (LPT)

  const int tid = threadIdx.x;
  const int wid = tid >> 6, lane = tid & 63;
  const int l31 = lane & 31, hi = lane >> 5;
  const int qbase = g * 128 + wid * 32;

  __shared__ __align__(16) unsigned char LDSraw[32768];   // 2 x 16KB [K 8KB | V 8KB]
  unsigned short* lbuf = (unsigned short*)LDSraw;

  const unsigned short* K3b = K3 + (size_t)b * 524288;
  const unsigned short* V3b = V3 + (size_t)b * 524288;
  const int jmax_w = 4 * g + wid;
  const int Jcap = 4 * g + 3;
  const int R = (Jcap >= h) ? ((Jcap - h) / 6 + 1) : 0;

  const unsigned short* qp = Qb + ((size_t)(b * T_ + qbase + l31) << 7) + hi * 8;
  bf16x8 qf[8];
#pragma unroll
  for (int c = 0; c < 8; c++) qf[c] = ld16g(qp + c * 16);

  const f32x16 z16 = {0.f,0.f,0.f,0.f,0.f,0.f,0.f,0.f,0.f,0.f,0.f,0.f,0.f,0.f,0.f,0.f};
  f32x16 o[4];
  o[0] = z16; o[1] = z16; o[2] = z16; o[3] = z16;
  float m = -1e30f, l = 0.f;
  const int addrbase = hi << 4;

  const unsigned short* sbase = (wid < 2) ? K3b : V3b;
  const int soff = (wid & 1) * 2048;
  const int region = ((wid >= 2) ? 4096 : 0) + soff;

  if (R > 0) {
    const unsigned short* s0 = sbase + (size_t)h * 4096 + soff + lane * 8;
    unsigned short* d0 = lbuf + region;
#pragma unroll
    for (int i = 0; i < 4; i++) async16(s0 + i * 512, d0 + i * 512);
  }

  for (int r = 0; r < R; r++) {
    const int cur = r & 1;
    if (r + 1 < R) {
      const int jS = h + 6 * (r + 1);
      const unsigned short* sN = sbase + (size_t)jS * 4096 + soff + lane * 8;
      unsigned short* dN = lbuf + (cur ^ 1) * 8192 + region;
#pragma unroll
      for (int i = 0; i < 4; i++) async16(sN + i * 512, dN + i * 512);
      asm volatile("s_waitcnt vmcnt(4)" ::: "memory");
    } else {
      asm volatile("s_waitcnt vmcnt(0)" ::: "memory");
    }
    __builtin_amdgcn_s_barrier();

    const int j = h + 6 * r;
    if (j <= jmax_w) {
      const unsigned short* Kl = lbuf + cur * 8192;
      const unsigned short* Vl = Kl + 4096;
      bf16x8 kf[8];
#pragma unroll
      for (int c = 0; c < 8; c++) kf[c] = ld16g(Kl + c * 512 + lane * 8);
      f32x16 s = z16;
      __builtin_amdgcn_s_setprio(1);
#pragma unroll
      for (int c = 0; c < 8; c++) s = mfma32(kf[c], qf[c], s);
      __builtin_amdgcn_s_setprio(0);

      bf16x8 vf[4][2];
#pragma unroll
      for (int dt = 0; dt < 4; dt++)
#pragma unroll
        for (int ks = 0; ks < 2; ks++)
          vf[dt][ks] = ld16g(Vl + (dt * 2 + ks) * 512 + lane * 8);

      if (j == jmax_w) {
        const int kvb = j << 5;
        const int qq = qbase + l31;
#pragma unroll
        for (int r2 = 0; r2 < 16; r2++) {
          const int c0 = (r2 & 3) + 8 * (r2 >> 2) + 4 * hi;
          if (kvb + c0 > qq) s[r2] = -1e30f;
        }
      }

      float pm = half_merge_max(vmax16(s));
      const bool skip = __all(pm - m <= 8.0f);
      float mn = skip ? m : fmaxf(m, pm);
#pragma unroll
      for (int r2 = 0; r2 < 16; r2++) s[r2] = exp2f(s[r2] - mn);
      float ps = half_merge_sum(vsum16(s));
      if (skip) {
        l = l + ps;
      } else {
        float al = exp2f(m - mn);
        m = mn;
        l = l * al + ps;
#pragma unroll
        for (int r2 = 0; r2 < 16; r2++) {
          const int addr = addrbase + 4 * ((r2 & 3) + 8 * (r2 >> 2));
          float alb = bpermf(addr, al);
          o[0][r2] *= alb; o[1][r2] *= alb; o[2][r2] *= alb; o[3][r2] *= alb;
        }
      }

      bf16x8 pa[2];
#pragma unroll
      for (int ks = 0; ks < 2; ks++) {
        const int gb = ks * 8;
        unsigned int xa = cvtpk(s[gb + 0], s[gb + 1]), xb = cvtpk(s[gb + 4], s[gb + 5]);
        swapu(xa, xb);
        unsigned int ya = cvtpk(s[gb + 2], s[gb + 3]), yb = cvtpk(s[gb + 6], s[gb + 7]);
        swapu(ya, yb);
        u32x4 pw; pw[0] = xa; pw[1] = ya; pw[2] = xb; pw[3] = yb;
        pa[ks] = __builtin_bit_cast(bf16x8, pw);
      }

      __builtin_amdgcn_s_setprio(1);
#pragma unroll
      for (int ks = 0; ks < 2; ks++)
#pragma unroll
        for (int dt = 0; dt < 4; dt++) o[dt] = mfma32(pa[ks], vf[dt][ks], o[dt]);
      __builtin_amdgcn_s_setprio(0);
    }
    __builtin_amdgcn_sched_barrier(0);
    __builtin_amdgcn_s_barrier();
  }

  unsigned char* Pb = Pw8 + (size_t)((b * 32 + g) * 6 + h) * PART_BYTES;
  unsigned short* Po = (unsigned short*)Pb;
  float* Pm = (float*)(Pb + 32768);
  float* Pl = (float*)(Pb + 33280);
#pragma unroll
  for (int r2 = 0; r2 < 16; r2++) {
    const int q128 = wid * 32 + (r2 & 3) + 8 * (r2 >> 2) + 4 * hi;
#pragma unroll
    for (int dt = 0; dt < 4; dt++)
      Po[q128 * 128 + dt * 32 + l31] = cvt1(o[dt][r2]);
  }
  if (lane < 32) { Pm[wid * 32 + l31] = m; Pl[wid * 32 + l31] = l; }
}

// ---------- kernel 4: merge 6 kv-slot partials, normalize, write Out ----------
// XCD-aligned block swizzle: attn wrote tile tl's 6 partials on XCD
// xcd(tl) = (tl>>5)*2 + (tl&1); per-XCD partial footprint = 26MB/8 = 3.25MB
// < 4MB L2. Mapping merge blocks to the same XCD turns the Pw reads into L2
// hits instead of cross-XCD L3/HBM traffic.
__global__ __launch_bounds__(256) void attn_merge_kernel(const unsigned char* __restrict__ Pw8,
                                                         float* __restrict__ Out) {
  const int bid = blockIdx.x;                      // 0..2047
  const int xcd = bid & 7, idx = bid >> 3;         // idx 0..255
  const int b = xcd >> 1;                          // matches attn: b = xcd>>1
  const int g = ((idx >> 4) << 1) | (xcd & 1);     // matches attn: g&1 = xcd&1
  const int tl = b * 32 + g;                       // tile 0..127
  const int inner = (idx & 15) * 256 + threadIdx.x; // 0..4095
  const int q = inner >> 5;                        // 0..127
  const int d = (inner & 31) * 4;
  const unsigned char* base = Pw8 + (size_t)tl * 6 * PART_BYTES;

  float mm[6], ll[6];
#pragma unroll
  for (int p = 0; p < 6; p++) {
    mm[p] = *(const float*)(base + p * PART_BYTES + 32768 + q * 4);
    ll[p] = *(const float*)(base + p * PART_BYTES + 33280 + q * 4);
  }
  float mn = mm[0];
#pragma unroll
  for (int p = 1; p < 6; p++) mn = fmaxf(mn, mm[p]);
  float f[6], denom = 0.f;
#pragma unroll
  for (int p = 0; p < 6; p++) { f[p] = exp2f(mm[p] - mn); denom += f[p] * ll[p]; }
  const float inv = 1.0f / denom;

  f32x4 acc = {0.f, 0.f, 0.f, 0.f};
#pragma unroll
  for (int p = 0; p < 6; p++) {
    const unsigned short* po = (const unsigned short*)(base + p * PART_BYTES) + q * 128 + d;
    unsigned long long v4 = *(const unsigned long long*)po;
    const unsigned short* pv = (const unsigned short*)&v4;
#pragma unroll
    for (int i = 0; i < 4; i++) acc[i] += f[p] * bf16_to_f32(pv[i]);
  }
#pragma unroll
  for (int i = 0; i < 4; i++) acc[i] *= inv;
  *(f32x4*)(Out + (size_t)(b * 4096 + g * 128 + q) * 128 + d) = acc;
}

// ---------- host ----------
extern "C" void kernel_launch(void* const* d_in, const int* in_sizes, int n_in,
                              void* d_out, int out_size, void* d_ws, size_t ws_size,
                              hipStream_t stream) {
  const float* X  = (const float*)d_in[0];
  const float* W0 = (const float*)d_in[1];
  const float* W1 = (const float*)d_in[2];
  const float* W2 = (const float*)d_in[3];
  float* Out = (float*)d_out;

  unsigned char* ws = (unsigned char*)d_ws;
  // WT (786KB, dead after qkv_fused) overlaps Pw (26MB, written by attn).
  unsigned short* WT = (unsigned short*)(ws);
  unsigned char* Pw  = ws;                                 // 768*33792 = 25,952,256 B
  unsigned short* Qb = (unsigned short*)(ws + 34078720);   //  4,194,304 B
  unsigned short* K3 = (unsigned short*)(ws + 38273024);   //  4,194,304 B
  unsigned short* V3 = (unsigned short*)(ws + 42467328);   //  4,194,304 B (end 46.66MB)

  const float qscale = 1.4426950408889634f / sqrtf(128.0f); // log2(e) * H^-0.5

  conv_w_kernel<<<dim3(1536), dim3(256), 0, stream>>>(W0, W1, W2, WT, qscale);
  qkv_fused_kernel<<<dim3(384), dim3(256), 0, stream>>>(X, WT, Qb, K3, V3);
  attn_kernel<<<dim3(768), dim3(256), 0, stream>>>(Qb, K3, V3, Pw);
  attn_merge_kernel<<<dim3(2048), dim3(256), 0, stream>>>(Pw, Out);
}

// Round 7
// 74.656 us; speedup vs baseline: 1.0384x; 1.0384x over previous
//
#include <hip/hip_runtime.h>
#include <math.h>

// ---------- types ----------
typedef __bf16 bf16x8 __attribute__((ext_vector_type(8)));
typedef float f32x4 __attribute__((ext_vector_type(4)));
typedef float f32x16 __attribute__((ext_vector_type(16)));
typedef unsigned int u32x4 __attribute__((ext_vector_type(4)));
typedef unsigned short u16x8 __attribute__((ext_vector_type(8)));

#define B_ 4
#define T_ 4096
#define C_ 1024
#define H_ 128

static __device__ __forceinline__ unsigned short f32_to_bf16(float f) {
  unsigned int u = __builtin_bit_cast(unsigned int, f);
  u += 0x7FFFu + ((u >> 16) & 1u);   // RNE
  return (unsigned short)(u >> 16);
}
static __device__ __forceinline__ float bf16_to_f32(unsigned short u) {
  unsigned int x = ((unsigned int)u) << 16;
  return __builtin_bit_cast(float, x);
}

static __device__ __forceinline__ bf16x8 ld16g(const unsigned short* p) {
  return __builtin_bit_cast(bf16x8, *(const u32x4*)p);
}

static __device__ __forceinline__ f32x4 mfma16(bf16x8 a, bf16x8 b, f32x4 c) {
  return __builtin_amdgcn_mfma_f32_16x16x32_bf16(a, b, c, 0, 0, 0);
}
static __device__ __forceinline__ f32x16 mfma32(bf16x8 a, bf16x8 b, f32x16 c) {
  return __builtin_amdgcn_mfma_f32_32x32x16_bf16(a, b, c, 0, 0, 0);
}

// v_permlane32_swap_b32: ONLY safe when a and b hold DIFFERENT values
// (R4 bug: identical SSA values coalesce onto one VGPR and the swap no-ops).
static __device__ __forceinline__ void swapu(unsigned int& a, unsigned int& b) {
  asm volatile("v_permlane32_swap_b32 %0, %1" : "+v"(a), "+v"(b));
}
static __device__ __forceinline__ unsigned int cvtpk(float lo, float hi) {
  unsigned int r;
  asm("v_cvt_pk_bf16_f32 %0, %1, %2" : "=v"(r) : "v"(lo), "v"(hi));
  return r;
}
// single f32 -> bf16 via v_cvt_pk (RNE, 1 VALU op vs ~4 for the bit-twiddle)
static __device__ __forceinline__ unsigned short cvt1(float v) {
  return (unsigned short)cvtpk(v, v);
}
static __device__ __forceinline__ float bpermf(int addr, float v) {
  return __builtin_bit_cast(float, __builtin_amdgcn_ds_bpermute(addr, __builtin_bit_cast(int, v)));
}
static __device__ __forceinline__ float half_merge_max(float x) {
  return fmaxf(x, __shfl_xor(x, 32));
}
static __device__ __forceinline__ float half_merge_sum(float x) {
  return x + __shfl_xor(x, 32);
}
static __device__ __forceinline__ float vmax16(f32x16 v) {
  float a0 = fmaxf(v[0], v[1]),  a1 = fmaxf(v[2], v[3]);
  float a2 = fmaxf(v[4], v[5]),  a3 = fmaxf(v[6], v[7]);
  float a4 = fmaxf(v[8], v[9]),  a5 = fmaxf(v[10], v[11]);
  float a6 = fmaxf(v[12], v[13]), a7 = fmaxf(v[14], v[15]);
  float b0 = fmaxf(a0, a1), b1 = fmaxf(a2, a3), b2 = fmaxf(a4, a5), b3 = fmaxf(a6, a7);
  return fmaxf(fmaxf(b0, b1), fmaxf(b2, b3));
}
static __device__ __forceinline__ float vsum16(f32x16 v) {
  float a0 = v[0] + v[1],  a1 = v[2] + v[3],  a2 = v[4] + v[5],  a3 = v[6] + v[7];
  float a4 = v[8] + v[9],  a5 = v[10] + v[11], a6 = v[12] + v[13], a7 = v[14] + v[15];
  float b0 = a0 + a1, b1 = a2 + a3, b2 = a4 + a5, b3 = a6 + a7;
  return (b0 + b1) + (b2 + b3);
}

typedef __attribute__((address_space(1))) const unsigned char as1_u8;
typedef __attribute__((address_space(3))) unsigned char as3_u8;
static __device__ __forceinline__ void async16(const void* g, void* l) {
  __builtin_amdgcn_global_load_lds((as1_u8*)g, (as3_u8*)l, 16, 0, 0);
}

// 8 f32 -> 8 bf16 via 4x v_cvt_pk_bf16_f32 (RNE, element order preserved).
static __device__ __forceinline__ u16x8 pack8cvt(float4 a, float4 b) {
  u32x4 u;
  u[0] = cvtpk(a.x, a.y); u[1] = cvtpk(a.z, a.w);
  u[2] = cvtpk(b.x, b.y); u[3] = cvtpk(b.z, b.w);
  return __builtin_bit_cast(u16x8, u);
}

#define PART_BYTES 33792   // bf16 O[128][128] (32768) + f32 m[128] (512) + f32 l[128] (512)

// ---------- kernel 1: W -> WT bf16 transposed; Wq scaled by log2e/sqrt(H) ----------
__global__ __launch_bounds__(256) void conv_w_kernel(const float* __restrict__ W0,
                                                     const float* __restrict__ W1,
                                                     const float* __restrict__ W2,
                                                     unsigned short* __restrict__ WT,
                                                     float qscale) {
  int tid = blockIdx.x * 256 + threadIdx.x;
  int o = tid >> 17;
  int r = tid & 131071;
  int n = r & 127;
  int k = r >> 7;
  const float* W = (o == 0) ? W0 : ((o == 1) ? W1 : W2);
  float v = W[r];
  if (o == 0) v *= qscale;
  WT[(size_t)o * 131072 + (size_t)n * 1024 + k] = f32_to_bf16(v);
}

// ---------- kernel 2: fused X-convert + QKV projection (64x384 tile, BK=64) ----------
// R7: FULL Q/K/V FUSION — X read ONCE. After six falsifications (occupancy R1,
// drain R2, barriers R4, rounds R5, event-count R6), the surviving theory is
// the latency x L3-traffic product on the X stream: R0-R6 all read X 3x (192MB,
// L3-tier — invisible in FETCH_SIZE) because Q/K/V ran as separate blocks.
// One block now computes all 384 cols for a 64-row tile: 512 thr = 8 waves in
// a 2x4 grid of 32x96 sub-tiles; At 8KB + Bt 48KB; 256 blocks = 1/CU,
// 2 waves/SIMD. Per-step chain is the shortest yet (6 B-asyncs + ONE A-pack).
// All swizzles are R3's proven 128B-row involutions (row&7 keys; 48/96 are
// multiples of 8 so &7 is preserved); epilogue reuses R5's proven nb>>7
// o-dispatch. B re-reads (192MB) hit per-XCD L2 (WT = 0.75MB L2-resident).
__global__ __launch_bounds__(512) void qkv_fused_kernel(const float* __restrict__ X,
                                                        const unsigned short* __restrict__ WT,
                                                        unsigned short* __restrict__ Qb,
                                                        unsigned short* __restrict__ K3,
                                                        unsigned short* __restrict__ V3) {
  __shared__ __align__(16) unsigned short At[64 * 64];     // 8KB
  __shared__ __align__(16) unsigned short Bt[384 * 64];    // 48KB
  const int rt = blockIdx.x;                // 64-row tile 0..255

  const float* Ax = X + (size_t)rt * 64 * 1024;

  const int tid = threadIdx.x;
  const int lane = tid & 63, wid = tid >> 6;   // wid 0..7
  const int l15 = lane & 15, lg = lane >> 4;
  const int wm = wid >> 2, wn = wid & 3;       // wave grid: 2 row x 4 col (32x96)
  const int srow = wid * 8 + (lane >> 3);      // A staging row 0..63
  const int scol = (lane & 7) * 8;             // A staging col (elements)
  const int swcol = scol ^ ((srow & 7) << 3);              // A LDS write col (swizzled)
  const int sbcol = (((lane & 7) ^ (lane >> 3)) << 3);     // B global src col (pre-swizzle)
  const int rsw = (l15 & 7) << 3;              // read-side XOR operand

  const f32x4 fzero = {0.f, 0.f, 0.f, 0.f};
  f32x4 acc[2][6];
#pragma unroll
  for (int i = 0; i < 2; i++)
#pragma unroll
    for (int j = 0; j < 6; j++) acc[i][j] = fzero;

  // A reg-prefetch for k-step 0 (one row, 8 f32 per lane)
  float4 fA0, fA1;
  {
    const float* xs = Ax + (size_t)srow * 1024 + scol;
    fA0 = *(const float4*)xs;
    fA1 = *(const float4*)(xs + 4);
  }

  for (int ks = 0; ks < 16; ks++) {
    const int k0 = ks * 64;
    __syncthreads();   // previous MFMA LDS reads complete
    // stage B: 384 rows, 48 rows/wave = 6 async16 (pre-swizzled global src)
#pragma unroll
    for (int j = 0; j < 6; j++) {
      const int row = wid * 48 + j * 8 + (lane >> 3);   // row&7 == lane>>3
      async16(WT + (size_t)row * 1024 + k0 + sbcol, &Bt[(wid * 48 + j * 8) * 64]);
    }
    // stage A (convert + swizzled ds_write, ONE pack per lane)
    *(u16x8*)(&At[srow * 64 + swcol]) = pack8cvt(fA0, fA1);
    __syncthreads();   // drains vmcnt (B) + lgkmcnt (A writes)
    // prefetch next k-step's A f32 (latency hidden under MFMA)
    if (ks + 1 < 16) {
      const float* xs = Ax + (size_t)srow * 1024 + (ks + 1) * 64 + scol;
      fA0 = *(const float4*)xs;
      fA1 = *(const float4*)(xs + 4);
    }
#pragma unroll
    for (int kk = 0; kk < 2; kk++) {
      bf16x8 af[2], bfr[6];
#pragma unroll
      for (int i = 0; i < 2; i++)
        af[i] = ld16g(&At[(wm * 32 + i * 16 + l15) * 64 + ((kk * 32 + lg * 8) ^ rsw)]);
#pragma unroll
      for (int j = 0; j < 6; j++)
        bfr[j] = ld16g(&Bt[(wn * 96 + j * 16 + l15) * 64 + ((kk * 32 + lg * 8) ^ rsw)]);
      __builtin_amdgcn_s_setprio(1);
#pragma unroll
      for (int i = 0; i < 2; i++)
#pragma unroll
        for (int j = 0; j < 6; j++) acc[i][j] = mfma16(af[i], bfr[j], acc[i][j]);
      __builtin_amdgcn_s_setprio(0);
    }
  }

  // epilogue: each 16-col fragment lies entirely in one o (128|16 alignment)
#pragma unroll
  for (int j = 0; j < 6; j++) {
    const int nb = wn * 96 + j * 16;   // output super-col base 0..368
    const int o = nb >> 7;             // 0=Q 1=K 2=V (wave-uniform)
    const int dbase = nb & 127;
    if (o == 0) {
#pragma unroll
      for (int i = 0; i < 2; i++)
#pragma unroll
        for (int r = 0; r < 4; r++) {
          int row = rt * 64 + wm * 32 + i * 16 + lg * 4 + r;
          int col = dbase + l15;
          Qb[(size_t)row * 128 + col] = cvt1(acc[i][j][r]);
        }
    } else if (o == 1) {
#pragma unroll
      for (int i = 0; i < 2; i++)
#pragma unroll
        for (int r = 0; r < 4; r++) {
          int token = rt * 64 + wm * 32 + i * 16 + lg * 4 + r;
          int d = dbase + l15;
          int bb = token >> 12, t = token & 4095;
          int t32 = t >> 5;
          int lane2 = (t & 31) | (((d >> 3) & 1) << 5);
          int c = d >> 4;
          int j2 = d & 7;
          K3[(size_t)(((bb * 128 + t32) * 8 + c) * 64 + lane2) * 8 + j2] = cvt1(acc[i][j][r]);
        }
    } else {
#pragma unroll
      for (int i = 0; i < 2; i++)
#pragma unroll
        for (int r = 0; r < 4; r++) {
          int token = rt * 64 + wm * 32 + i * 16 + lg * 4 + r;
          int d = dbase + l15;
          int bb = token >> 12, tt = token & 4095;
          int t32 = tt >> 5;
          int kss = (tt >> 4) & 1;
          int hi2 = (tt >> 3) & 1;
          int j2 = tt & 7;
          int dt = d >> 5;
          int lane2 = (d & 31) | (hi2 << 5);
          V3[(size_t)(((bb * 128 + t32) * 8 + dt * 2 + kss) * 64 + lane2) * 8 + j2] = cvt1(acc[i][j][r]);
        }
    }
  }
}

// ---------- kernel 3: causal flash attention, 128-row blocks, shared KV tile ----------
// Grid 768 = 4b x 32 q-tiles(128 rows) x 6 kv-slots; 4 warps = 4 qg share one
// 32-token KV tile per round (16KB staging, 32KB dbuf). Counted vmcnt(4) + raw
// barriers (T3/T4); in-reg swapped-QK softmax + T12 P-pack + T13 defer-max.
// Partial: bf16 O + f32 m/l -> Pw; separate merge kernel combines (the fused
// last-block merge regressed 2.6x — __threadfence() = per-block L2 flush on
// non-coherent XCDs, R20 post-mortem).
__global__ __launch_bounds__(256, 2) void attn_kernel(const unsigned short* __restrict__ Qb,
                                                      const unsigned short* __restrict__ K3,
                                                      const unsigned short* __restrict__ V3,
                                                      unsigned char* __restrict__ Pw8) {
  const int bid = blockIdx.x;
  const int xcd = bid & 7;
  const int b = xcd >> 1;
  const int rest = bid >> 3;                  // 0..95
  const int h = rest % 6;                     // kv slot
  const int jj = rest / 6;                    // 0..15
  const int g = (xcd & 1) + 2 * (15 - jj);    // q-tile 0..31, heavy-first (LPT)

  const int tid = threadIdx.x;
  const int wid = tid >> 6, lane = tid & 63;
  const int l31 = lane & 31, hi = lane >> 5;
  const int qbase = g * 128 + wid * 32;

  __shared__ __align__(16) unsigned char LDSraw[32768];   // 2 x 16KB [K 8KB | V 8KB]
  unsigned short* lbuf = (unsigned short*)LDSraw;

  const unsigned short* K3b = K3 + (size_t)b * 524288;
  const unsigned short* V3b = V3 + (size_t)b * 524288;
  const int jmax_w = 4 * g + wid;
  const int Jcap = 4 * g + 3;
  const int R = (Jcap >= h) ? ((Jcap - h) / 6 + 1) : 0;

  const unsigned short* qp = Qb + ((size_t)(b * T_ + qbase + l31) << 7) + hi * 8;
  bf16x8 qf[8];
#pragma unroll
  for (int c = 0; c < 8; c++) qf[c] = ld16g(qp + c * 16);

  const f32x16 z16 = {0.f,0.f,0.f,0.f,0.f,0.f,0.f,0.f,0.f,0.f,0.f,0.f,0.f,0.f,0.f,0.f};
  f32x16 o[4];
  o[0] = z16; o[1] = z16; o[2] = z16; o[3] = z16;
  float m = -1e30f, l = 0.f;
  const int addrbase = hi << 4;

  const unsigned short* sbase = (wid < 2) ? K3b : V3b;
  const int soff = (wid & 1) * 2048;
  const int region = ((wid >= 2) ? 4096 : 0) + soff;

  if (R > 0) {
    const unsigned short* s0 = sbase + (size_t)h * 4096 + soff + lane * 8;
    unsigned short* d0 = lbuf + region;
#pragma unroll
    for (int i = 0; i < 4; i++) async16(s0 + i * 512, d0 + i * 512);
  }

  for (int r = 0; r < R; r++) {
    const int cur = r & 1;
    if (r + 1 < R) {
      const int jS = h + 6 * (r + 1);
      const unsigned short* sN = sbase + (size_t)jS * 4096 + soff + lane * 8;
      unsigned short* dN = lbuf + (cur ^ 1) * 8192 + region;
#pragma unroll
      for (int i = 0; i < 4; i++) async16(sN + i * 512, dN + i * 512);
      asm volatile("s_waitcnt vmcnt(4)" ::: "memory");
    } else {
      asm volatile("s_waitcnt vmcnt(0)" ::: "memory");
    }
    __builtin_amdgcn_s_barrier();

    const int j = h + 6 * r;
    if (j <= jmax_w) {
      const unsigned short* Kl = lbuf + cur * 8192;
      const unsigned short* Vl = Kl + 4096;
      bf16x8 kf[8];
#pragma unroll
      for (int c = 0; c < 8; c++) kf[c] = ld16g(Kl + c * 512 + lane * 8);
      f32x16 s = z16;
      __builtin_amdgcn_s_setprio(1);
#pragma unroll
      for (int c = 0; c < 8; c++) s = mfma32(kf[c], qf[c], s);
      __builtin_amdgcn_s_setprio(0);

      bf16x8 vf[4][2];
#pragma unroll
      for (int dt = 0; dt < 4; dt++)
#pragma unroll
        for (int ks = 0; ks < 2; ks++)
          vf[dt][ks] = ld16g(Vl + (dt * 2 + ks) * 512 + lane * 8);

      if (j == jmax_w) {
        const int kvb = j << 5;
        const int qq = qbase + l31;
#pragma unroll
        for (int r2 = 0; r2 < 16; r2++) {
          const int c0 = (r2 & 3) + 8 * (r2 >> 2) + 4 * hi;
          if (kvb + c0 > qq) s[r2] = -1e30f;
        }
      }

      float pm = half_merge_max(vmax16(s));
      const bool skip = __all(pm - m <= 8.0f);
      float mn = skip ? m : fmaxf(m, pm);
#pragma unroll
      for (int r2 = 0; r2 < 16; r2++) s[r2] = exp2f(s[r2] - mn);
      float ps = half_merge_sum(vsum16(s));
      if (skip) {
        l = l + ps;
      } else {
        float al = exp2f(m - mn);
        m = mn;
        l = l * al + ps;
#pragma unroll
        for (int r2 = 0; r2 < 16; r2++) {
          const int addr = addrbase + 4 * ((r2 & 3) + 8 * (r2 >> 2));
          float alb = bpermf(addr, al);
          o[0][r2] *= alb; o[1][r2] *= alb; o[2][r2] *= alb; o[3][r2] *= alb;
        }
      }

      bf16x8 pa[2];
#pragma unroll
      for (int ks = 0; ks < 2; ks++) {
        const int gb = ks * 8;
        unsigned int xa = cvtpk(s[gb + 0], s[gb + 1]), xb = cvtpk(s[gb + 4], s[gb + 5]);
        swapu(xa, xb);
        unsigned int ya = cvtpk(s[gb + 2], s[gb + 3]), yb = cvtpk(s[gb + 6], s[gb + 7]);
        swapu(ya, yb);
        u32x4 pw; pw[0] = xa; pw[1] = ya; pw[2] = xb; pw[3] = yb;
        pa[ks] = __builtin_bit_cast(bf16x8, pw);
      }

      __builtin_amdgcn_s_setprio(1);
#pragma unroll
      for (int ks = 0; ks < 2; ks++)
#pragma unroll
        for (int dt = 0; dt < 4; dt++) o[dt] = mfma32(pa[ks], vf[dt][ks], o[dt]);
      __builtin_amdgcn_s_setprio(0);
    }
    __builtin_amdgcn_sched_barrier(0);
    __builtin_amdgcn_s_barrier();
  }

  unsigned char* Pb = Pw8 + (size_t)((b * 32 + g) * 6 + h) * PART_BYTES;
  unsigned short* Po = (unsigned short*)Pb;
  float* Pm = (float*)(Pb + 32768);
  float* Pl = (float*)(Pb + 33280);
#pragma unroll
  for (int r2 = 0; r2 < 16; r2++) {
    const int q128 = wid * 32 + (r2 & 3) + 8 * (r2 >> 2) + 4 * hi;
#pragma unroll
    for (int dt = 0; dt < 4; dt++)
      Po[q128 * 128 + dt * 32 + l31] = cvt1(o[dt][r2]);
  }
  if (lane < 32) { Pm[wid * 32 + l31] = m; Pl[wid * 32 + l31] = l; }
}

// ---------- kernel 4: merge 6 kv-slot partials, normalize, write Out ----------
// XCD-aligned block swizzle: attn wrote tile tl's 6 partials on XCD
// xcd(tl) = (tl>>5)*2 + (tl&1); per-XCD partial footprint = 26MB/8 = 3.25MB
// < 4MB L2. Mapping merge blocks to the same XCD turns the Pw reads into L2
// hits instead of cross-XCD L3/HBM traffic.
__global__ __launch_bounds__(256) void attn_merge_kernel(const unsigned char* __restrict__ Pw8,
                                                         float* __restrict__ Out) {
  const int bid = blockIdx.x;                      // 0..2047
  const int xcd = bid & 7, idx = bid >> 3;         // idx 0..255
  const int b = xcd >> 1;                          // matches attn: b = xcd>>1
  const int g = ((idx >> 4) << 1) | (xcd & 1);     // matches attn: g&1 = xcd&1
  const int tl = b * 32 + g;                       // tile 0..127
  const int inner = (idx & 15) * 256 + threadIdx.x; // 0..4095
  const int q = inner >> 5;                        // 0..127
  const int d = (inner & 31) * 4;
  const unsigned char* base = Pw8 + (size_t)tl * 6 * PART_BYTES;

  float mm[6], ll[6];
#pragma unroll
  for (int p = 0; p < 6; p++) {
    mm[p] = *(const float*)(base + p * PART_BYTES + 32768 + q * 4);
    ll[p] = *(const float*)(base + p * PART_BYTES + 33280 + q * 4);
  }
  float mn = mm[0];
#pragma unroll
  for (int p = 1; p < 6; p++) mn = fmaxf(mn, mm[p]);
  float f[6], denom = 0.f;
#pragma unroll
  for (int p = 0; p < 6; p++) { f[p] = exp2f(mm[p] - mn); denom += f[p] * ll[p]; }
  const float inv = 1.0f / denom;

  f32x4 acc = {0.f, 0.f, 0.f, 0.f};
#pragma unroll
  for (int p = 0; p < 6; p++) {
    const unsigned short* po = (const unsigned short*)(base + p * PART_BYTES) + q * 128 + d;
    unsigned long long v4 = *(const unsigned long long*)po;
    const unsigned short* pv = (const unsigned short*)&v4;
#pragma unroll
    for (int i = 0; i < 4; i++) acc[i] += f[p] * bf16_to_f32(pv[i]);
  }
#pragma unroll
  for (int i = 0; i < 4; i++) acc[i] *= inv;
  *(f32x4*)(Out + (size_t)(b * 4096 + g * 128 + q) * 128 + d) = acc;
}

// ---------- host ----------
extern "C" void kernel_launch(void* const* d_in, const int* in_sizes, int n_in,
                              void* d_out, int out_size, void* d_ws, size_t ws_size,
                              hipStream_t stream) {
  const float* X  = (const float*)d_in[0];
  const float* W0 = (const float*)d_in[1];
  const float* W1 = (const float*)d_in[2];
  const float* W2 = (const float*)d_in[3];
  float* Out = (float*)d_out;

  unsigned char* ws = (unsigned char*)d_ws;
  // WT (786KB, dead after qkv_fused) overlaps Pw (26MB, written by attn).
  unsigned short* WT = (unsigned short*)(ws);
  unsigned char* Pw  = ws;                                 // 768*33792 = 25,952,256 B
  unsigned short* Qb = (unsigned short*)(ws + 34078720);   //  4,194,304 B
  unsigned short* K3 = (unsigned short*)(ws + 38273024);   //  4,194,304 B
  unsigned short* V3 = (unsigned short*)(ws + 42467328);   //  4,194,304 B (end 46.66MB)

  const float qscale = 1.4426950408889634f / sqrtf(128.0f); // log2(e) * H^-0.5

  conv_w_kernel<<<dim3(1536), dim3(256), 0, stream>>>(W0, W1, W2, WT, qscale);
  qkv_fused_kernel<<<dim3(256), dim3(512), 0, stream>>>(X, WT, Qb, K3, V3);
  attn_kernel<<<dim3(768), dim3(256), 0, stream>>>(Qb, K3, V3, Pw);
  attn_merge_kernel<<<dim3(2048), dim3(256), 0, stream>>>(Pw, Out);
}